// Round 1
// baseline (167.137 us; speedup 1.0000x reference)
//
#include <hip/hip_runtime.h>

// ---------------------------------------------------------------------------
// TreeEncoder fused MFMA kernel (bf16 inputs to matrix cores, fp32 accumulate)
//   B=256 batches, N=512 nodes, F=64, H=128, L=2 layers
//   M = B*N = 131072 rows, each row independent until the final mean over N.
// ---------------------------------------------------------------------------

typedef short bf16x8 __attribute__((ext_vector_type(8)));
typedef float f32x4  __attribute__((ext_vector_type(4)));

#define MFMA16(a, b, c) __builtin_amdgcn_mfma_f32_16x16x32_bf16((a), (b), (c), 0, 0, 0)

__device__ __forceinline__ unsigned short f2bf(float f) {
    unsigned int u = __float_as_uint(f);
    unsigned int r = (u + 0x7fffu + ((u >> 16) & 1u)) >> 16;  // RNE
    return (unsigned short)r;
}

__device__ __forceinline__ float fsigmoid(float x) {
    return 1.0f / (1.0f + __expf(-x));
}

__device__ __forceinline__ float ftanh(float x) {
    x = fminf(fmaxf(x, -10.0f), 10.0f);
    float e = __expf(2.0f * x);
    return (e - 1.0f) / (e + 1.0f);
}

// ---------------------------------------------------------------------------
// Prep: reformat weights into MFMA B-fragment-ready bf16 layout in ws.
//   B-frag convention (16x16x32): lane l holds B[k][n] with n = 16*t + (l&15),
//   k = 32*kk + 8*(l>>4) + e, e=0..7.  Stored as 1KB blocks: [fragblock][lane][e].
//   ws map (bytes):
//     [0      , 16384)  emb_W  frags: fb = t*2 + kk            (t<8, kk<2)
//     [16384  , 212992) gate   frags: fb = ((layer*3+g)*8+t)*4+kk
// ---------------------------------------------------------------------------
__global__ void prep_frags(const float* __restrict__ embW,
                           const float* __restrict__ Wi,
                           const float* __restrict__ Wo,
                           const float* __restrict__ Wc,
                           char* __restrict__ ws) {
    int fb = blockIdx.x;          // 0..207
    int l  = threadIdx.x;         // 0..63
    int g  = l >> 4, c0 = l & 15;

    const float* src;
    int t, kk;
    if (fb < 16) {
        t = fb >> 1; kk = fb & 1;
        src = embW;                                   // [64][128]
    } else {
        int r = fb - 16;                              // 0..191
        int layer = r / 96;  r %= 96;
        int gate  = r / 32;  r %= 32;
        t = r >> 2; kk = r & 3;
        const float* Ws[3] = {Wi, Wo, Wc};
        src = Ws[gate] + (size_t)layer * 128 * 128;   // [128][128]
    }

    bf16x8 v;
#pragma unroll
    for (int e = 0; e < 8; ++e) {
        int k   = kk * 32 + g * 8 + e;
        int col = t * 16 + c0;
        v[e] = (short)f2bf(src[(size_t)k * 128 + col]);
    }
    *reinterpret_cast<bf16x8*>(ws + (size_t)fb * 1024 + l * 16) = v;
}

// ---------------------------------------------------------------------------
// Main fused kernel: 1024 blocks x 256 threads; wave w owns 32 rows.
// ---------------------------------------------------------------------------
__global__ __launch_bounds__(256) void tree_enc(
        const float* __restrict__ X,       // [131072][64]
        const float* __restrict__ emb_b,   // [128]
        const float* __restrict__ bWi, const float* __restrict__ bUi,
        const float* __restrict__ bWo, const float* __restrict__ bUo,
        const float* __restrict__ bWc, const float* __restrict__ bUc,
        const char*  __restrict__ frags,   // ws
        float* __restrict__ out) {         // [256][128]

    // per-wave private transpose buffer; 136 = 128 + 8 pad (A-frag reads bank-uniform)
    __shared__ __align__(16) unsigned short hbuf[4][32][136];

    const int tid = threadIdx.x;
    const int w   = tid >> 6;
    const int l   = tid & 63;
    const int g   = l >> 4;           // k-group
    const int c0  = l & 15;           // col within 16-tile (and A row)
    const int rowbase = blockIdx.x * 128 + w * 32;
    const int b  = blockIdx.x >> 2;   // 4 blocks per batch

    // ---------------- embedding: h0 = X @ embW + emb_b ----------------
    {
        bf16x8 afr[2][2];             // [mtile][kk], K=64
#pragma unroll
        for (int m = 0; m < 2; ++m) {
#pragma unroll
            for (int kk = 0; kk < 2; ++kk) {
                int row = rowbase + m * 16 + c0;
                const float4* p = reinterpret_cast<const float4*>(
                        X + (size_t)row * 64 + kk * 32 + g * 8);
                float4 v0 = p[0], v1 = p[1];
                bf16x8 a;
                a[0] = (short)f2bf(v0.x); a[1] = (short)f2bf(v0.y);
                a[2] = (short)f2bf(v0.z); a[3] = (short)f2bf(v0.w);
                a[4] = (short)f2bf(v1.x); a[5] = (short)f2bf(v1.y);
                a[6] = (short)f2bf(v1.z); a[7] = (short)f2bf(v1.w);
                afr[m][kk] = a;
            }
        }
        const f32x4 z4 = {0.f, 0.f, 0.f, 0.f};
#pragma unroll
        for (int t = 0; t < 8; ++t) {
            f32x4 acc[2] = {z4, z4};
#pragma unroll
            for (int kk = 0; kk < 2; ++kk) {
                bf16x8 bf = *reinterpret_cast<const bf16x8*>(
                        frags + ((size_t)(t * 2 + kk) * 64 + l) * 16);
                acc[0] = MFMA16(afr[0][kk], bf, acc[0]);
                acc[1] = MFMA16(afr[1][kk], bf, acc[1]);
            }
            float bias = emb_b[t * 16 + c0];
#pragma unroll
            for (int m = 0; m < 2; ++m)
#pragma unroll
                for (int r = 0; r < 4; ++r)
                    hbuf[w][m * 16 + g * 4 + r][t * 16 + c0] =
                        f2bf(acc[m][r] + bias);   // C layout: col=l&15, row=4*(l>>4)+r
        }
    }

    // ---------------- 2 TreeLSTM layers ----------------
    float msum[8];
#pragma unroll
    for (int t = 0; t < 8; ++t) msum[t] = 0.f;

    const f32x4 z4 = {0.f, 0.f, 0.f, 0.f};
#pragma unroll
    for (int layer = 0; layer < 2; ++layer) {
        // A-fragments of h from LDS (reads complete before this layer's writes)
        bf16x8 A[2][4];
#pragma unroll
        for (int m = 0; m < 2; ++m)
#pragma unroll
            for (int kk = 0; kk < 4; ++kk)
                A[m][kk] = *reinterpret_cast<const bf16x8*>(
                        &hbuf[w][m * 16 + c0][kk * 32 + g * 8]);

        const char* fW = frags + 16384 + (size_t)layer * 98304;
        const int bofs = layer * 128;

#pragma unroll
        for (int t = 0; t < 8; ++t) {
            f32x4 ai[2] = {z4, z4}, ao[2] = {z4, z4}, ac[2] = {z4, z4};
#pragma unroll
            for (int kk = 0; kk < 4; ++kk) {
                bf16x8 bi = *reinterpret_cast<const bf16x8*>(
                        fW + ((size_t)((0 * 8 + t) * 4 + kk) * 64 + l) * 16);
                bf16x8 bo = *reinterpret_cast<const bf16x8*>(
                        fW + ((size_t)((1 * 8 + t) * 4 + kk) * 64 + l) * 16);
                bf16x8 bc = *reinterpret_cast<const bf16x8*>(
                        fW + ((size_t)((2 * 8 + t) * 4 + kk) * 64 + l) * 16);
#pragma unroll
                for (int m = 0; m < 2; ++m) {
                    ai[m] = MFMA16(A[m][kk], bi, ai[m]);
                    ao[m] = MFMA16(A[m][kk], bo, ao[m]);
                    ac[m] = MFMA16(A[m][kk], bc, ac[m]);
                }
            }
            const int c = t * 16 + c0;
            const float Bi = bWi[bofs + c] + bUi[bofs + c];
            const float Bo = bWo[bofs + c] + bUo[bofs + c];
            const float Bc = bWc[bofs + c] + bUc[bofs + c];
#pragma unroll
            for (int m = 0; m < 2; ++m) {
#pragma unroll
                for (int r = 0; r < 4; ++r) {
                    float iv = fsigmoid(ai[m][r] + Bi);
                    float ov = fsigmoid(ao[m][r] + Bo);
                    float cv = ftanh(ac[m][r] + Bc);
                    float h  = ov * ftanh(iv * cv);
                    if (layer == 1) {
                        msum[t] += h;                       // last layer: mean partial
                    } else {
                        hbuf[w][m * 16 + g * 4 + r][c] = f2bf(h);
                    }
                }
            }
        }
    }

    // ---------------- mean over nodes ----------------
    // lane holds col c=16t+c0 partial over its 8 rows; xor-reduce over g-groups.
#pragma unroll
    for (int t = 0; t < 8; ++t) {
        float v = msum[t];
        v += __shfl_xor(v, 16);
        v += __shfl_xor(v, 32);
        if (g == 0)
            atomicAdd(&out[b * 128 + t * 16 + c0], v * (1.0f / 512.0f));
    }
}

// ---------------------------------------------------------------------------
extern "C" void kernel_launch(void* const* d_in, const int* in_sizes, int n_in,
                              void* d_out, int out_size, void* d_ws, size_t ws_size,
                              hipStream_t stream) {
    const float* X    = (const float*)d_in[0];
    const float* embW = (const float*)d_in[1];
    const float* embb = (const float*)d_in[2];
    const float* Wi   = (const float*)d_in[3];
    const float* Wo   = (const float*)d_in[4];
    const float* Wc   = (const float*)d_in[5];
    const float* bWi  = (const float*)d_in[6];
    const float* bUi  = (const float*)d_in[7];
    const float* bWo  = (const float*)d_in[8];
    const float* bUo  = (const float*)d_in[9];
    const float* bWc  = (const float*)d_in[10];
    const float* bUc  = (const float*)d_in[11];
    float* out = (float*)d_out;
    char*  ws  = (char*)d_ws;

    hipMemsetAsync(d_out, 0, (size_t)out_size * sizeof(float), stream);
    prep_frags<<<208, 64, 0, stream>>>(embW, Wi, Wo, Wc, ws);
    tree_enc<<<1024, 256, 0, stream>>>(X, embb, bWi, bUi, bWo, bUo, bWc, bUc,
                                       (const char*)ws, out);
}

// Round 2
// 96.095 us; speedup vs baseline: 1.7393x; 1.7393x over previous
//
#include <hip/hip_runtime.h>

// ---------------------------------------------------------------------------
// TreeEncoder fused MFMA kernel, round 2.
//   Changes vs round 1:
//   - 64 rows per wave (halves weight-fragment L2 traffic, 2x MFMA per load)
//   - fast activations: v_rcp instead of precise fp32 division
//   - 2-op bf16 conversion (round-half-up) instead of 4-op RNE
//   - per-t contiguous fragment layout (12 KB streaming chunk per t-iter)
//   - cross-wave LDS reduction -> 4x fewer global atomics
// ---------------------------------------------------------------------------

typedef short bf16x8 __attribute__((ext_vector_type(8)));
typedef float f32x4  __attribute__((ext_vector_type(4)));

#define MFMA16(a, b, c) __builtin_amdgcn_mfma_f32_16x16x32_bf16((a), (b), (c), 0, 0, 0)

__device__ __forceinline__ unsigned short f2bf(float f) {
    // round-half-up: one bf16-ulp class error, same scale as bf16 quantization
    return (unsigned short)((__float_as_uint(f) + 0x8000u) >> 16);
}

__device__ __forceinline__ float frcp(float x) { return __builtin_amdgcn_rcpf(x); }

__device__ __forceinline__ float fsigmoid(float x) {
    // 1/(1+e^-x); saturates correctly at +-inf without clamping
    return frcp(1.0f + __expf(-x));
}

__device__ __forceinline__ float ftanh(float x) {
    x = fminf(fmaxf(x, -10.0f), 10.0f);     // keep e finite
    float e = __expf(2.0f * x);
    return (e - 1.0f) * frcp(e + 1.0f);
}

// ---------------------------------------------------------------------------
// Prep: weights -> MFMA B-fragment bf16 layout in ws.
//   B-frag (16x16x32): lane l holds B[k][n], n = 16*t + (l&15),
//   k = 32*kk + 8*(l>>4) + e.  1KB blocks: [block][lane][16B].
//   ws map (bytes):
//     [0, 16384)       emb_W: block = t*2 + kk                      (t<8, kk<2)
//     [16384, 212992)  gates: block = (layer*8 + t)*12 + gate*4 + kk
//       -> the 12 fragments used by one t-iteration are CONTIGUOUS (12 KB)
// ---------------------------------------------------------------------------
__global__ void prep_frags(const float* __restrict__ embW,
                           const float* __restrict__ Wi,
                           const float* __restrict__ Wo,
                           const float* __restrict__ Wc,
                           char* __restrict__ ws) {
    int fb = blockIdx.x;          // 0..207
    int l  = threadIdx.x;         // 0..63
    int g  = l >> 4, c0 = l & 15;

    const float* src;
    int t, kk;
    size_t dst;
    if (fb < 16) {
        t = fb >> 1; kk = fb & 1;
        src = embW;                                   // [64][128]
        dst = (size_t)fb * 1024;
    } else {
        int r = fb - 16;                              // 0..191 == (layer*8+t)*12+gate*4+kk
        int layer = r / 96;
        int r2 = r % 96;
        t = r2 / 12;
        int r3 = r2 % 12;
        int gate = r3 >> 2;
        kk = r3 & 3;
        const float* Ws[3] = {Wi, Wo, Wc};
        src = Ws[gate] + (size_t)layer * 128 * 128;   // [128][128]
        dst = 16384 + (size_t)r * 1024;
    }

    bf16x8 v;
#pragma unroll
    for (int e = 0; e < 8; ++e) {
        int k   = kk * 32 + g * 8 + e;
        int col = t * 16 + c0;
        v[e] = (short)f2bf(src[(size_t)k * 128 + col]);
    }
    *reinterpret_cast<bf16x8*>(ws + dst + (size_t)l * 16) = v;
}

// ---------------------------------------------------------------------------
// Main fused kernel: 512 blocks x 256 threads; each wave owns 64 rows.
// ---------------------------------------------------------------------------
__global__ __launch_bounds__(256, 2) void tree_enc(
        const float* __restrict__ X,       // [131072][64]
        const float* __restrict__ emb_b,   // [128]
        const float* __restrict__ bWi, const float* __restrict__ bUi,
        const float* __restrict__ bWo, const float* __restrict__ bUo,
        const float* __restrict__ bWc, const float* __restrict__ bUc,
        const char*  __restrict__ frags,   // ws
        float* __restrict__ out) {         // [256][128]

    // per-wave transpose buffer; 136 = 128 + 8 pad (A-frag ds_read_b128 spread)
    __shared__ __align__(16) unsigned short hbuf[4][64][136];
    __shared__ float redbuf[4][128];

    const int tid = threadIdx.x;
    const int w   = tid >> 6;
    const int l   = tid & 63;
    const int g   = l >> 4;           // k-group
    const int c0  = l & 15;           // col within 16-tile / A row
    const int rowbase = blockIdx.x * 256 + w * 64;
    const int b  = blockIdx.x >> 1;   // 2 blocks per batch

    // ---------------- embedding: h0 = X @ embW + emb_b ----------------
    {
        bf16x8 afr[4][2];             // [mtile][kk], K=64
#pragma unroll
        for (int mi = 0; mi < 4; ++mi) {
#pragma unroll
            for (int kk = 0; kk < 2; ++kk) {
                int row = rowbase + mi * 16 + c0;
                const float4* p = reinterpret_cast<const float4*>(
                        X + (size_t)row * 64 + kk * 32 + g * 8);
                float4 v0 = p[0], v1 = p[1];
                bf16x8 a;
                a[0] = (short)f2bf(v0.x); a[1] = (short)f2bf(v0.y);
                a[2] = (short)f2bf(v0.z); a[3] = (short)f2bf(v0.w);
                a[4] = (short)f2bf(v1.x); a[5] = (short)f2bf(v1.y);
                a[6] = (short)f2bf(v1.z); a[7] = (short)f2bf(v1.w);
                afr[mi][kk] = a;
            }
        }
        const f32x4 z4 = {0.f, 0.f, 0.f, 0.f};
#pragma unroll
        for (int t = 0; t < 8; ++t) {
            f32x4 acc[4] = {z4, z4, z4, z4};
#pragma unroll
            for (int kk = 0; kk < 2; ++kk) {
                bf16x8 bf = *reinterpret_cast<const bf16x8*>(
                        frags + ((size_t)(t * 2 + kk) * 64 + l) * 16);
#pragma unroll
                for (int mi = 0; mi < 4; ++mi)
                    acc[mi] = MFMA16(afr[mi][kk], bf, acc[mi]);
            }
            float bias = emb_b[t * 16 + c0];
#pragma unroll
            for (int mi = 0; mi < 4; ++mi)
#pragma unroll
                for (int r = 0; r < 4; ++r)
                    hbuf[w][mi * 16 + g * 4 + r][t * 16 + c0] =
                        f2bf(acc[mi][r] + bias);   // C layout: col=l&15, row=4*(l>>4)+r
        }
    }

    // ---------------- 2 TreeLSTM layers ----------------
    float msum[8];
#pragma unroll
    for (int t = 0; t < 8; ++t) msum[t] = 0.f;

    const f32x4 z4 = {0.f, 0.f, 0.f, 0.f};
#pragma unroll
    for (int layer = 0; layer < 2; ++layer) {
        // A-fragments of h from LDS (wave-private slice; DS ops in-order per wave)
        bf16x8 A[4][4];
#pragma unroll
        for (int mi = 0; mi < 4; ++mi)
#pragma unroll
            for (int kk = 0; kk < 4; ++kk)
                A[mi][kk] = *reinterpret_cast<const bf16x8*>(
                        &hbuf[w][mi * 16 + c0][kk * 32 + g * 8]);

        const char* fW = frags + 16384 + (size_t)layer * 98304;
        const int bofs = layer * 128;

#pragma unroll
        for (int t = 0; t < 8; ++t) {
            const char* ft = fW + (size_t)t * 12288 + (size_t)l * 16;
            f32x4 ai[4] = {z4, z4, z4, z4};
            f32x4 ao[4] = {z4, z4, z4, z4};
            f32x4 ac[4] = {z4, z4, z4, z4};
#pragma unroll
            for (int kk = 0; kk < 4; ++kk) {
                bf16x8 bi = *reinterpret_cast<const bf16x8*>(ft + (size_t)(0 + kk) * 1024);
                bf16x8 bo = *reinterpret_cast<const bf16x8*>(ft + (size_t)(4 + kk) * 1024);
                bf16x8 bc = *reinterpret_cast<const bf16x8*>(ft + (size_t)(8 + kk) * 1024);
#pragma unroll
                for (int mi = 0; mi < 4; ++mi) {
                    ai[mi] = MFMA16(A[mi][kk], bi, ai[mi]);
                    ao[mi] = MFMA16(A[mi][kk], bo, ao[mi]);
                    ac[mi] = MFMA16(A[mi][kk], bc, ac[mi]);
                }
            }
            const int c = t * 16 + c0;
            const float Bi = bWi[bofs + c] + bUi[bofs + c];
            const float Bo = bWo[bofs + c] + bUo[bofs + c];
            const float Bc = bWc[bofs + c] + bUc[bofs + c];
#pragma unroll
            for (int mi = 0; mi < 4; ++mi) {
#pragma unroll
                for (int r = 0; r < 4; ++r) {
                    float iv = fsigmoid(ai[mi][r] + Bi);
                    float ov = fsigmoid(ao[mi][r] + Bo);
                    float cv = ftanh(ac[mi][r] + Bc);
                    float h  = ov * ftanh(iv * cv);
                    if (layer == 1) {
                        msum[t] += h;                       // mean partial
                    } else {
                        hbuf[w][mi * 16 + g * 4 + r][c] = f2bf(h);
                    }
                }
            }
        }
    }

    // ---------------- mean over nodes ----------------
    // lane holds col c=16t+c0 summed over its 16 rows; xor-reduce over g.
#pragma unroll
    for (int t = 0; t < 8; ++t) {
        float v = msum[t];
        v += __shfl_xor(v, 16);
        v += __shfl_xor(v, 32);
        if (g == 0) redbuf[w][t * 16 + c0] = v;
    }
    __syncthreads();
    if (tid < 128) {
        float s = redbuf[0][tid] + redbuf[1][tid] + redbuf[2][tid] + redbuf[3][tid];
        atomicAdd(&out[b * 128 + tid], s * (1.0f / 512.0f));
    }
}

// ---------------------------------------------------------------------------
extern "C" void kernel_launch(void* const* d_in, const int* in_sizes, int n_in,
                              void* d_out, int out_size, void* d_ws, size_t ws_size,
                              hipStream_t stream) {
    const float* X    = (const float*)d_in[0];
    const float* embW = (const float*)d_in[1];
    const float* embb = (const float*)d_in[2];
    const float* Wi   = (const float*)d_in[3];
    const float* Wo   = (const float*)d_in[4];
    const float* Wc   = (const float*)d_in[5];
    const float* bWi  = (const float*)d_in[6];
    const float* bUi  = (const float*)d_in[7];
    const float* bWo  = (const float*)d_in[8];
    const float* bUo  = (const float*)d_in[9];
    const float* bWc  = (const float*)d_in[10];
    const float* bUc  = (const float*)d_in[11];
    float* out = (float*)d_out;
    char*  ws  = (char*)d_ws;

    hipMemsetAsync(d_out, 0, (size_t)out_size * sizeof(float), stream);
    prep_frags<<<208, 64, 0, stream>>>(embW, Wi, Wo, Wc, ws);
    tree_enc<<<512, 256, 0, stream>>>(X, embb, bWi, bUi, bWo, bUo, bWc, bUc,
                                      (const char*)ws, out);
}